// Round 1
// baseline (7380.814 us; speedup 1.0000x reference)
//
#include <hip/hip_runtime.h>
#include <hip/hip_bf16.h>

#define VV 50257
#define DD 256
#define HH 512
#define BB 64
#define SS 512
#define H3 1536

typedef _Float16 f16x8 __attribute__((ext_vector_type(8)));
typedef float f32x4 __attribute__((ext_vector_type(4)));

// ---------------------------------------------------------------------------
// K1: xp[s][b][0:1536] = emb[tokens[b][s]] @ W + b0      (f16 out, f32 acc)
// grid: (12 n-tiles of 128 cols, 512 s), 256 threads (4 waves = 4 M-tiles)
// ---------------------------------------------------------------------------
__global__ __launch_bounds__(256) void k1_embed_proj(
    const int* __restrict__ tokens, const float* __restrict__ emb,
    const float* __restrict__ W, const float* __restrict__ bias,
    _Float16* __restrict__ xp)
{
    const int s  = blockIdx.y;
    const int nt = blockIdx.x;          // 128-col tile
    const int tid = threadIdx.x;
    __shared__ _Float16 aLds[64 * 256]; // 32 KB, row stride 512 B, swizzled

    // stage A: 64 batch rows x 256 k (emb gather, f32 -> f16)
    for (int c = tid; c < 64 * 32; c += 256) {
        int row = c >> 5, kc = c & 31;
        int tok = tokens[row * SS + s];
        const float* src = emb + (size_t)tok * DD + kc * 8;
        float4 f0 = *(const float4*)(src);
        float4 f1 = *(const float4*)(src + 4);
        f16x8 v;
        v[0]=(_Float16)f0.x; v[1]=(_Float16)f0.y; v[2]=(_Float16)f0.z; v[3]=(_Float16)f0.w;
        v[4]=(_Float16)f1.x; v[5]=(_Float16)f1.y; v[6]=(_Float16)f1.z; v[7]=(_Float16)f1.w;
        int byte = row * 512 + ((kc * 16) ^ ((row & 7) << 4));
        *(f16x8*)((char*)aLds + byte) = v;
    }
    __syncthreads();

    const int w = tid >> 6, l = tid & 63;
    const int l15 = l & 15, lk = l >> 4;
    const int colbase = nt * 128;
    f32x4 acc[8] = {};

    for (int ks = 0; ks < 8; ++ks) {
        int arow = 16 * w + l15;
        int abyte = arow * 512 + ((((ks * 32 + lk * 8) * 2)) ^ ((arow & 7) << 4));
        f16x8 aFrag = *(const f16x8*)((const char*)aLds + abyte);
        int krow = ks * 32 + lk * 8;
        #pragma unroll
        for (int ns = 0; ns < 8; ++ns) {
            int col = colbase + ns * 16 + l15;
            const float* wp = W + (size_t)krow * H3 + col;
            f16x8 bFrag;
            #pragma unroll
            for (int i = 0; i < 8; ++i) bFrag[i] = (_Float16)wp[(size_t)i * H3];
            acc[ns] = __builtin_amdgcn_mfma_f32_16x16x32_f16(aFrag, bFrag, acc[ns], 0, 0, 0);
        }
    }
    #pragma unroll
    for (int ns = 0; ns < 8; ++ns) {
        int col = colbase + ns * 16 + l15;
        float b0 = bias[col];
        #pragma unroll
        for (int i = 0; i < 4; ++i) {
            int row = 16 * w + lk * 4 + i;
            xp[((size_t)s * BB + row) * H3 + col] = (_Float16)(acc[ns][i] + b0);
        }
    }
}

// ---------------------------------------------------------------------------
// K2: one GRU step.  rec = h@U + b1 ; gates ; h_out.
// grid: 32 WGs (16 hidden units each => 48 U cols), 256 threads (4 M-tiles)
// ---------------------------------------------------------------------------
__global__ __launch_bounds__(256) void k2_gru_step(
    const float* __restrict__ hin, float* __restrict__ hout,
    const _Float16* __restrict__ xp, const float* __restrict__ U,
    const float* __restrict__ bias, const int* __restrict__ tokens, int t)
{
    const int g = blockIdx.x;           // hidden slice base jg = g*16
    const int tid = threadIdx.x;
    __shared__ _Float16 hLds[64 * 512]; // 64 KB, row stride 1024 B, swizzled

    for (int c = tid; c < 64 * 64; c += 256) {
        int row = c >> 6, kc = c & 63;
        const float* src = hin + row * HH + kc * 8;
        float4 f0 = *(const float4*)(src);
        float4 f1 = *(const float4*)(src + 4);
        f16x8 v;
        v[0]=(_Float16)f0.x; v[1]=(_Float16)f0.y; v[2]=(_Float16)f0.z; v[3]=(_Float16)f0.w;
        v[4]=(_Float16)f1.x; v[5]=(_Float16)f1.y; v[6]=(_Float16)f1.z; v[7]=(_Float16)f1.w;
        int byte = row * 1024 + ((kc * 16) ^ ((row & 7) << 4));
        *(f16x8*)((char*)hLds + byte) = v;
    }
    __syncthreads();

    const int w = tid >> 6, l = tid & 63;
    const int l15 = l & 15, lk = l >> 4;
    const int jg = g * 16;
    f32x4 az = {}, ar = {}, ah = {};

    for (int ks = 0; ks < 16; ++ks) {
        int arow = 16 * w + l15;
        int abyte = arow * 1024 + ((((ks * 32 + lk * 8) * 2)) ^ ((arow & 7) << 4));
        f16x8 aFrag = *(const f16x8*)((const char*)hLds + abyte);
        int krow = ks * 32 + lk * 8;
        const float* uz = U + (size_t)krow * H3 + jg + l15;
        f16x8 bz, br, bh;
        #pragma unroll
        for (int i = 0; i < 8; ++i) {
            bz[i] = (_Float16)uz[(size_t)i * H3];
            br[i] = (_Float16)uz[(size_t)i * H3 + 512];
            bh[i] = (_Float16)uz[(size_t)i * H3 + 1024];
        }
        az = __builtin_amdgcn_mfma_f32_16x16x32_f16(aFrag, bz, az, 0, 0, 0);
        ar = __builtin_amdgcn_mfma_f32_16x16x32_f16(aFrag, br, ar, 0, 0, 0);
        ah = __builtin_amdgcn_mfma_f32_16x16x32_f16(aFrag, bh, ah, 0, 0, 0);
    }

    int j = jg + l15;
    float b1z = bias[H3 + j], b1r = bias[H3 + 512 + j], b1h = bias[H3 + 1024 + j];
    #pragma unroll
    for (int i = 0; i < 4; ++i) {
        int row = 16 * w + lk * 4 + i;
        float rz = az[i] + b1z, rr = ar[i] + b1r, rh = ah[i] + b1h;
        const _Float16* xq = xp + ((size_t)t * BB + row) * H3;
        float xz = (float)xq[j], xr = (float)xq[512 + j], xh = (float)xq[1024 + j];
        float hold = hin[row * HH + j];
        float z = 1.f / (1.f + expf(-(xz + rz)));
        float r = 1.f / (1.f + expf(-(xr + rr)));
        float hcand = tanhf(xh + r * rh);
        float hn = z * hold + (1.f - z) * hcand;
        if (tokens[row * SS + t] == 0) hn = hold;
        hout[row * HH + j] = hn;
    }
}

// ---------------------------------------------------------------------------
// K3a: logits = h_last @ Wd + bd -> d_out (raw); per-WG softmax partials
// grid: 393 col-tiles of 128, 256 threads
// ---------------------------------------------------------------------------
__global__ __launch_bounds__(256) void k3_logits(
    const float* __restrict__ hin, const float* __restrict__ Wd,
    const float* __restrict__ bd, float* __restrict__ out,
    float* __restrict__ partials)
{
    const int nt = blockIdx.x;
    const int tid = threadIdx.x;
    __shared__ _Float16 hLds[64 * 512];

    for (int c = tid; c < 64 * 64; c += 256) {
        int row = c >> 6, kc = c & 63;
        const float* src = hin + row * HH + kc * 8;
        float4 f0 = *(const float4*)(src);
        float4 f1 = *(const float4*)(src + 4);
        f16x8 v;
        v[0]=(_Float16)f0.x; v[1]=(_Float16)f0.y; v[2]=(_Float16)f0.z; v[3]=(_Float16)f0.w;
        v[4]=(_Float16)f1.x; v[5]=(_Float16)f1.y; v[6]=(_Float16)f1.z; v[7]=(_Float16)f1.w;
        int byte = row * 1024 + ((kc * 16) ^ ((row & 7) << 4));
        *(f16x8*)((char*)hLds + byte) = v;
    }
    __syncthreads();

    const int w = tid >> 6, l = tid & 63;
    const int l15 = l & 15, lk = l >> 4;
    f32x4 acc[8] = {};

    for (int ks = 0; ks < 16; ++ks) {
        int arow = 16 * w + l15;
        int abyte = arow * 1024 + ((((ks * 32 + lk * 8) * 2)) ^ ((arow & 7) << 4));
        f16x8 aFrag = *(const f16x8*)((const char*)hLds + abyte);
        int krow = ks * 32 + lk * 8;
        #pragma unroll
        for (int ns = 0; ns < 8; ++ns) {
            int col = nt * 128 + ns * 16 + l15;
            f16x8 bFrag;
            if (col < VV) {
                #pragma unroll
                for (int i = 0; i < 8; ++i) bFrag[i] = (_Float16)Wd[(size_t)(krow + i) * VV + col];
            } else {
                #pragma unroll
                for (int i = 0; i < 8; ++i) bFrag[i] = (_Float16)0.f;
            }
            acc[ns] = __builtin_amdgcn_mfma_f32_16x16x32_f16(aFrag, bFrag, acc[ns], 0, 0, 0);
        }
    }

    // epilogue: store raw logits, online (max,sumexp) per row
    float lg[8][4];
    float m[4] = {-3.4e38f, -3.4e38f, -3.4e38f, -3.4e38f};
    float ss[4] = {0.f, 0.f, 0.f, 0.f};
    #pragma unroll
    for (int ns = 0; ns < 8; ++ns) {
        int col = nt * 128 + ns * 16 + l15;
        bool ok = col < VV;
        float bv = ok ? bd[col] : 0.f;
        #pragma unroll
        for (int i = 0; i < 4; ++i) {
            int row = 16 * w + lk * 4 + i;
            float v = acc[ns][i] + bv;
            lg[ns][i] = ok ? v : -3.4e38f;
            if (ok) {
                out[(size_t)row * VV + col] = v;
                m[i] = fmaxf(m[i], v);
            }
        }
    }
    #pragma unroll
    for (int i = 0; i < 4; ++i) {
        #pragma unroll
        for (int ns = 0; ns < 8; ++ns)
            if (lg[ns][i] > -3.3e38f) ss[i] += __expf(lg[ns][i] - m[i]);
        // reduce across the 16 lanes sharing the same rows (l>>4 fixed)
        for (int d = 1; d < 16; d <<= 1) {
            float m2 = __shfl_xor(m[i], d);
            float s2 = __shfl_xor(ss[i], d);
            float nM = fmaxf(m[i], m2);
            ss[i] = ss[i] * __expf(m[i] - nM) + s2 * __expf(m2 - nM);
            m[i] = nM;
        }
        if (l15 == 0) {
            int row = 16 * w + lk * 4 + i;
            partials[((size_t)nt * 64 + row) * 2 + 0] = m[i];
            partials[((size_t)nt * 64 + row) * 2 + 1] = ss[i];
        }
    }
}

// K3b: combine 393 partials per row -> rowMS[64][2]
__global__ __launch_bounds__(64) void k3_reduce(
    const float* __restrict__ partials, float* __restrict__ rowMS)
{
    int row = blockIdx.x, l = threadIdx.x;
    float M = -3.4e38f, Ssum = 0.f;
    for (int p = l; p < 393; p += 64) {
        float mp = partials[((size_t)p * 64 + row) * 2 + 0];
        float sp = partials[((size_t)p * 64 + row) * 2 + 1];
        float nM = fmaxf(M, mp);
        Ssum = Ssum * __expf(M - nM) + sp * __expf(mp - nM);
        M = nM;
    }
    for (int d = 1; d < 64; d <<= 1) {
        float m2 = __shfl_xor(M, d), s2 = __shfl_xor(Ssum, d);
        float nM = fmaxf(M, m2);
        Ssum = Ssum * __expf(M - nM) + s2 * __expf(m2 - nM);
        M = nM;
    }
    if (l == 0) { rowMS[row * 2] = M; rowMS[row * 2 + 1] = Ssum; }
}

// K3c: out = exp(out - M_row) / S_row, in place
__global__ __launch_bounds__(256) void k3_softmax(
    float* __restrict__ out, const float* __restrict__ rowMS)
{
    int col = blockIdx.x * 256 + threadIdx.x;
    int row = blockIdx.y;
    if (col < VV) {
        float M = rowMS[row * 2], Sv = rowMS[row * 2 + 1];
        size_t idx = (size_t)row * VV + col;
        out[idx] = __expf(out[idx] - M) / Sv;
    }
}

// ---------------------------------------------------------------------------
extern "C" void kernel_launch(void* const* d_in, const int* in_sizes, int n_in,
                              void* d_out, int out_size, void* d_ws, size_t ws_size,
                              hipStream_t stream) {
    const int*   tokens = (const int*)  d_in[0];
    const float* emb    = (const float*)d_in[1];
    const float* W      = (const float*)d_in[2];
    const float* U      = (const float*)d_in[3];
    const float* bias   = (const float*)d_in[4];
    const float* Wd     = (const float*)d_in[5];
    const float* bd     = (const float*)d_in[6];
    float* out = (float*)d_out;

    const size_t XP_BYTES = (size_t)SS * BB * H3 * 2;   // 100,663,296
    const size_t H_BYTES  = (size_t)BB * HH * 4;        // 131,072
    const size_t P_BYTES  = (size_t)393 * 64 * 2 * 4;   // 201,216

    char* ws = (char*)d_ws;
    _Float16* xp    = (_Float16*)ws;
    float* hbuf0    = (float*)(ws + XP_BYTES);
    float* hbuf1    = (float*)(ws + XP_BYTES + H_BYTES);
    float* partials = (float*)(ws + XP_BYTES + 2 * H_BYTES);
    float* rowMS    = (float*)(ws + XP_BYTES + 2 * H_BYTES + P_BYTES);

    hipMemsetAsync(hbuf0, 0, H_BYTES, stream);

    k1_embed_proj<<<dim3(12, 512), 256, 0, stream>>>(tokens, emb, W, bias, xp);

    for (int t = 0; t < SS; ++t) {
        const float* hin  = (t & 1) ? hbuf1 : hbuf0;
        float*       hout = (t & 1) ? hbuf0 : hbuf1;
        k2_gru_step<<<32, 256, 0, stream>>>(hin, hout, xp, U, bias, tokens, t);
    }
    // after t=511 (odd), final state is in hbuf0

    k3_logits<<<393, 256, 0, stream>>>(hbuf0, Wd, bd, out, partials);
    k3_reduce<<<64, 64, 0, stream>>>(partials, rowMS);
    k3_softmax<<<dim3((VV + 255) / 256, BB), 256, 0, stream>>>(out, rowMS);
}

// Round 2
// 3634.985 us; speedup vs baseline: 2.0305x; 2.0305x over previous
//
#include <hip/hip_runtime.h>
#include <hip/hip_bf16.h>

#define VV 50257
#define DD 256
#define HH 512
#define BB 64
#define SS 512
#define H3 1536
#define NWG 32          // scan workgroups (1 per CU, co-resident)
#define JSL 16          // hidden units per scan WG
#define UCOLS 48        // 3 gates * JSL
#define UBYTES (UCOLS*HH*2)   // 49152 B  (f16 U slice image)
#define HBYTES (BB*HH*2)      // 65536 B  (f16 h image)

typedef _Float16 f16x8 __attribute__((ext_vector_type(8)));
typedef _Float16 f16x4 __attribute__((ext_vector_type(4)));
typedef float f32x4 __attribute__((ext_vector_type(4)));

#define AS1 __attribute__((address_space(1)))
#define AS3 __attribute__((address_space(3)))
#define GLL16(g, s) __builtin_amdgcn_global_load_lds((const AS1 char*)(g), (AS3 char*)(s), 16, 0, 0)

// ---------------------------------------------------------------------------
// Pack W (f32 [256][1536]) -> f16 k-major: elem (k,col) at [(k>>3)*1536+col]*8 + (k&7)
// ---------------------------------------------------------------------------
__global__ __launch_bounds__(256) void kPackW(const float* __restrict__ W,
                                              _Float16* __restrict__ wsW) {
    int idx = blockIdx.x * 256 + threadIdx.x;     // 32 kb * 1536 col
    int kb = idx / H3, col = idx % H3;
    f16x8 v;
    #pragma unroll
    for (int e = 0; e < 8; ++e) v[e] = (_Float16)W[(size_t)(kb*8+e)*H3 + col];
    *(f16x8*)(wsW + (size_t)idx*8) = v;
}

// ---------------------------------------------------------------------------
// Pack U (f32 [512][1536]) -> per-WG f16 LDS images: WG w holds cols
// {g*512 + w*16 + jl : g=0..2, jl=0..15}, k-major packed (48 cols x 512 k).
// ---------------------------------------------------------------------------
__global__ __launch_bounds__(256) void kPackU(const float* __restrict__ U,
                                              _Float16* __restrict__ wsU) {
    int wgp = blockIdx.x;                          // 32
    for (int idx = threadIdx.x; idx < 64*UCOLS; idx += 256) {
        int kb = idx / UCOLS, col = idx % UCOLS;
        int g = col / JSL, jl = col % JSL;
        int gcol = g*HH + wgp*JSL + jl;
        f16x8 v;
        #pragma unroll
        for (int e = 0; e < 8; ++e) v[e] = (_Float16)U[(size_t)(kb*8+e)*H3 + gcol];
        *(f16x8*)(wsU + (size_t)wgp*(64*UCOLS*8) + (size_t)idx*8) = v;
    }
}

// ---------------------------------------------------------------------------
// K1: xp[t][col][b] (f16) = (emb[tokens] @ W + b0), packed for scan-side reads
// ---------------------------------------------------------------------------
__global__ __launch_bounds__(256) void k1_embed_proj(
    const int* __restrict__ tokens, const float* __restrict__ emb,
    const _Float16* __restrict__ wsW, const float* __restrict__ bias,
    _Float16* __restrict__ xp)
{
    const int s  = blockIdx.y;
    const int nt = blockIdx.x;
    const int tid = threadIdx.x;
    __shared__ _Float16 aLds[64 * 256];

    for (int c = tid; c < 64 * 32; c += 256) {
        int row = c >> 5, kc = c & 31;
        int tok = tokens[row * SS + s];
        const float* src = emb + (size_t)tok * DD + kc * 8;
        float4 f0 = *(const float4*)(src);
        float4 f1 = *(const float4*)(src + 4);
        f16x8 v;
        v[0]=(_Float16)f0.x; v[1]=(_Float16)f0.y; v[2]=(_Float16)f0.z; v[3]=(_Float16)f0.w;
        v[4]=(_Float16)f1.x; v[5]=(_Float16)f1.y; v[6]=(_Float16)f1.z; v[7]=(_Float16)f1.w;
        int byte = row * 512 + ((kc * 16) ^ ((row & 7) << 4));
        *(f16x8*)((char*)aLds + byte) = v;
    }
    __syncthreads();

    const int w = tid >> 6, l = tid & 63;
    const int l15 = l & 15, lk = l >> 4;
    const int colbase = nt * 128;
    f32x4 acc[8] = {};

    for (int ks = 0; ks < 8; ++ks) {
        int arow = 16 * w + l15;
        f16x8 aF = *(const f16x8*)((const char*)aLds + arow*512 + (((ks*32 + lk*8)*2) ^ ((arow & 7) << 4)));
        int kb = ks*4 + lk;
        #pragma unroll
        for (int ns = 0; ns < 8; ++ns) {
            int col = colbase + ns * 16 + l15;
            f16x8 bF = *(const f16x8*)(wsW + ((size_t)kb * H3 + col) * 8);
            acc[ns] = __builtin_amdgcn_mfma_f32_16x16x32_f16(aF, bF, acc[ns], 0, 0, 0);
        }
    }
    #pragma unroll
    for (int ns = 0; ns < 8; ++ns) {
        int col = colbase + ns * 16 + l15;
        float b0 = bias[col];
        f16x4 vv;
        #pragma unroll
        for (int i = 0; i < 4; ++i) vv[i] = (_Float16)(acc[ns][i] + b0);
        *(f16x4*)(xp + ((size_t)s * H3 + col) * BB + 16*w + lk*4) = vv;
    }
}

// ---------------------------------------------------------------------------
// K2: persistent GRU scan. 32 WGs x 128 thr; U slice resident in LDS;
// h exchanged via double-buffered global f16 image + device-scope flags.
// ---------------------------------------------------------------------------
__global__ __launch_bounds__(128) void k2_scan(
    const _Float16* __restrict__ xp, const _Float16* __restrict__ wsU,
    const float* __restrict__ bias, const int* __restrict__ tokens,
    char* __restrict__ hpub, float* __restrict__ hlast,
    unsigned int* __restrict__ flags)
{
    extern __shared__ char lds[];
    char* uLds = lds;              // 49152
    char* hLds = lds + UBYTES;     // 65536
    const int wg = blockIdx.x, tid = threadIdx.x;
    const int w = tid >> 6, l = tid & 63;
    const int l15 = l & 15, lk = l >> 4;
    const int jg = wg * JSL;
    const int j = jg + l15;

    // stage resident U slice (linear image -> linear LDS)
    {
        const char* src = (const char*)wsU + (size_t)wg * UBYTES;
        for (int c = w; c < UBYTES/1024; c += 2)
            GLL16(src + c*1024 + l*16, uLds + c*1024);
    }
    const float b1z = bias[H3 + j];
    const float b1r = bias[H3 + HH + j];
    const float b1h = bias[H3 + 2*HH + j];
    float hold[2][4] = {};
    __syncthreads();

    for (int t = 0; t < SS; ++t) {
        // issue gate-phase loads early (independent of the barrier)
        f16x4 xv0m0 = *(const f16x4*)(xp + ((size_t)t*H3 + 0*HH + j)*BB + w*32 + 0*16 + lk*4);
        f16x4 xv0m1 = *(const f16x4*)(xp + ((size_t)t*H3 + 0*HH + j)*BB + w*32 + 1*16 + lk*4);
        f16x4 xv1m0 = *(const f16x4*)(xp + ((size_t)t*H3 + 1*HH + j)*BB + w*32 + 0*16 + lk*4);
        f16x4 xv1m1 = *(const f16x4*)(xp + ((size_t)t*H3 + 1*HH + j)*BB + w*32 + 1*16 + lk*4);
        f16x4 xv2m0 = *(const f16x4*)(xp + ((size_t)t*H3 + 2*HH + j)*BB + w*32 + 0*16 + lk*4);
        f16x4 xv2m1 = *(const f16x4*)(xp + ((size_t)t*H3 + 2*HH + j)*BB + w*32 + 1*16 + lk*4);
        int tok[2][4];
        #pragma unroll
        for (int mt = 0; mt < 2; ++mt)
            #pragma unroll
            for (int i = 0; i < 4; ++i)
                tok[mt][i] = tokens[(w*32 + mt*16 + lk*4 + i)*SS + t];

        // wait for h(t) from all WGs
        if (t > 0) {
            if (tid < NWG) {
                unsigned int* fp = flags + tid * 16;
                int n = 0;
                while (__hip_atomic_load(fp, __ATOMIC_RELAXED, __HIP_MEMORY_SCOPE_AGENT) < (unsigned)t) {
                    if (++n > 3000000) break;   // safety bound
                }
            }
            __syncthreads();
            __threadfence();   // acquire: invalidate stale L1/L2 before reading h
        }
        // stage h(t) image -> LDS
        const char* hsrc = hpub + (size_t)(t & 1) * HBYTES;
        for (int c = w; c < HBYTES/1024; c += 2)
            GLL16(hsrc + c*1024 + l*16, hLds + c*1024);
        __syncthreads();

        // rec = h @ Uslice : 2 m-tiles x 3 gate-tiles per wave
        f32x4 a00 = {}, a01 = {}, a02 = {}, a10 = {}, a11 = {}, a12 = {};
        #pragma unroll 4
        for (int ks = 0; ks < 16; ++ks) {
            int kby = (ks*32 + lk*8) * 2;
            int sw  = (l15 & 7) << 4;
            const char* ar = hLds + (w*32 + l15) * 1024 + (kby ^ sw);
            f16x8 af0 = *(const f16x8*)(ar);
            f16x8 af1 = *(const f16x8*)(ar + 16*1024);
            const char* ub = uLds + ((ks*4 + lk)*UCOLS + l15) * 16;
            f16x8 bz = *(const f16x8*)(ub);
            f16x8 br = *(const f16x8*)(ub + 256);
            f16x8 bh = *(const f16x8*)(ub + 512);
            a00 = __builtin_amdgcn_mfma_f32_16x16x32_f16(af0, bz, a00, 0, 0, 0);
            a01 = __builtin_amdgcn_mfma_f32_16x16x32_f16(af0, br, a01, 0, 0, 0);
            a02 = __builtin_amdgcn_mfma_f32_16x16x32_f16(af0, bh, a02, 0, 0, 0);
            a10 = __builtin_amdgcn_mfma_f32_16x16x32_f16(af1, bz, a10, 0, 0, 0);
            a11 = __builtin_amdgcn_mfma_f32_16x16x32_f16(af1, br, a11, 0, 0, 0);
            a12 = __builtin_amdgcn_mfma_f32_16x16x32_f16(af1, bh, a12, 0, 0, 0);
        }

        // gates + publish h(t+1)
        char* hnxt = hpub + (size_t)((t+1) & 1) * HBYTES;
        #pragma unroll
        for (int mt = 0; mt < 2; ++mt) {
            f32x4 az = mt ? a10 : a00;
            f32x4 ar_ = mt ? a11 : a01;
            f32x4 ah = mt ? a12 : a02;
            f16x4 xz4 = mt ? xv0m1 : xv0m0;
            f16x4 xr4 = mt ? xv1m1 : xv1m0;
            f16x4 xh4 = mt ? xv2m1 : xv2m0;
            #pragma unroll
            for (int i = 0; i < 4; ++i) {
                int r = w*32 + mt*16 + lk*4 + i;
                float rz = az[i] + b1z;
                float rr = ar_[i] + b1r;
                float rh = ah[i] + b1h;
                float xz = (float)xz4[i], xr = (float)xr4[i], xh = (float)xh4[i];
                float z  = 1.f / (1.f + __expf(-(xz + rz)));
                float rg = 1.f / (1.f + __expf(-(xr + rr)));
                float ag = xh + rg * rh;
                float hc = 1.f - 2.f / (__expf(2.f * ag) + 1.f);   // stable tanh
                float hn = z * hold[mt][i] + (1.f - z) * hc;
                if (tok[mt][i] == 0) hn = hold[mt][i];
                hold[mt][i] = hn;
                if (t < SS-1) {
                    *(_Float16*)(hnxt + r*1024 + ((2*j) ^ ((r & 7) << 4))) = (_Float16)hn;
                } else {
                    hlast[r*HH + j] = hn;
                }
            }
        }
        if (t < SS-1) {
            __syncthreads();                     // all publish stores drained (vmcnt0 before barrier)
            if (tid == 0) {
                __threadfence();                 // flush to coherence point (L3)
                __hip_atomic_store(flags + wg*16, (unsigned)(t+1),
                                   __ATOMIC_RELAXED, __HIP_MEMORY_SCOPE_AGENT);
            }
        }
    }
}

// ---------------------------------------------------------------------------
// K3a: logits + per-WG softmax partials (unchanged from round 1)
// ---------------------------------------------------------------------------
__global__ __launch_bounds__(256) void k3_logits(
    const float* __restrict__ hin, const float* __restrict__ Wd,
    const float* __restrict__ bd, float* __restrict__ out,
    float* __restrict__ partials)
{
    const int nt = blockIdx.x;
    const int tid = threadIdx.x;
    __shared__ _Float16 hLds[64 * 512];

    for (int c = tid; c < 64 * 64; c += 256) {
        int row = c >> 6, kc = c & 63;
        const float* src = hin + row * HH + kc * 8;
        float4 f0 = *(const float4*)(src);
        float4 f1 = *(const float4*)(src + 4);
        f16x8 v;
        v[0]=(_Float16)f0.x; v[1]=(_Float16)f0.y; v[2]=(_Float16)f0.z; v[3]=(_Float16)f0.w;
        v[4]=(_Float16)f1.x; v[5]=(_Float16)f1.y; v[6]=(_Float16)f1.z; v[7]=(_Float16)f1.w;
        int byte = row * 1024 + ((kc * 16) ^ ((row & 7) << 4));
        *(f16x8*)((char*)hLds + byte) = v;
    }
    __syncthreads();

    const int w = tid >> 6, l = tid & 63;
    const int l15 = l & 15, lk = l >> 4;
    f32x4 acc[8] = {};

    for (int ks = 0; ks < 16; ++ks) {
        int arow = 16 * w + l15;
        int abyte = arow * 1024 + ((((ks * 32 + lk * 8) * 2)) ^ ((arow & 7) << 4));
        f16x8 aFrag = *(const f16x8*)((const char*)hLds + abyte);
        int krow = ks * 32 + lk * 8;
        #pragma unroll
        for (int ns = 0; ns < 8; ++ns) {
            int col = nt * 128 + ns * 16 + l15;
            f16x8 bFrag;
            if (col < VV) {
                #pragma unroll
                for (int i = 0; i < 8; ++i) bFrag[i] = (_Float16)Wd[(size_t)(krow + i) * VV + col];
            } else {
                #pragma unroll
                for (int i = 0; i < 8; ++i) bFrag[i] = (_Float16)0.f;
            }
            acc[ns] = __builtin_amdgcn_mfma_f32_16x16x32_f16(aFrag, bFrag, acc[ns], 0, 0, 0);
        }
    }

    float lg[8][4];
    float m[4] = {-3.4e38f, -3.4e38f, -3.4e38f, -3.4e38f};
    float ss[4] = {0.f, 0.f, 0.f, 0.f};
    #pragma unroll
    for (int ns = 0; ns < 8; ++ns) {
        int col = nt * 128 + ns * 16 + l15;
        bool ok = col < VV;
        float bv = ok ? bd[col] : 0.f;
        #pragma unroll
        for (int i = 0; i < 4; ++i) {
            int row = 16 * w + lk * 4 + i;
            float v = acc[ns][i] + bv;
            lg[ns][i] = ok ? v : -3.4e38f;
            if (ok) {
                out[(size_t)row * VV + col] = v;
                m[i] = fmaxf(m[i], v);
            }
        }
    }
    #pragma unroll
    for (int i = 0; i < 4; ++i) {
        #pragma unroll
        for (int ns = 0; ns < 8; ++ns)
            if (lg[ns][i] > -3.3e38f) ss[i] += __expf(lg[ns][i] - m[i]);
        for (int d = 1; d < 16; d <<= 1) {
            float m2 = __shfl_xor(m[i], d);
            float s2 = __shfl_xor(ss[i], d);
            float nM = fmaxf(m[i], m2);
            ss[i] = ss[i] * __expf(m[i] - nM) + s2 * __expf(m2 - nM);
            m[i] = nM;
        }
        if (l15 == 0) {
            int row = 16 * w + lk * 4 + i;
            partials[((size_t)nt * 64 + row) * 2 + 0] = m[i];
            partials[((size_t)nt * 64 + row) * 2 + 1] = ss[i];
        }
    }
}

__global__ __launch_bounds__(64) void k3_reduce(
    const float* __restrict__ partials, float* __restrict__ rowMS)
{
    int row = blockIdx.x, l = threadIdx.x;
    float M = -3.4e38f, Ssum = 0.f;
    for (int p = l; p < 393; p += 64) {
        float mp = partials[((size_t)p * 64 + row) * 2 + 0];
        float sp = partials[((size_t)p * 64 + row) * 2 + 1];
        float nM = fmaxf(M, mp);
        Ssum = Ssum * __expf(M - nM) + sp * __expf(mp - nM);
        M = nM;
    }
    for (int d = 1; d < 64; d <<= 1) {
        float m2 = __shfl_xor(M, d), s2 = __shfl_xor(Ssum, d);
        float nM = fmaxf(M, m2);
        Ssum = Ssum * __expf(M - nM) + s2 * __expf(m2 - nM);
        M = nM;
    }
    if (l == 0) { rowMS[row * 2] = M; rowMS[row * 2 + 1] = Ssum; }
}

__global__ __launch_bounds__(256) void k3_softmax(
    float* __restrict__ out, const float* __restrict__ rowMS)
{
    int col = blockIdx.x * 256 + threadIdx.x;
    int row = blockIdx.y;
    if (col < VV) {
        float M = rowMS[row * 2], Sv = rowMS[row * 2 + 1];
        size_t idx = (size_t)row * VV + col;
        out[idx] = __expf(out[idx] - M) / Sv;
    }
}

// ---------------------------------------------------------------------------
extern "C" void kernel_launch(void* const* d_in, const int* in_sizes, int n_in,
                              void* d_out, int out_size, void* d_ws, size_t ws_size,
                              hipStream_t stream) {
    const int*   tokens = (const int*)  d_in[0];
    const float* emb    = (const float*)d_in[1];
    const float* W      = (const float*)d_in[2];
    const float* U      = (const float*)d_in[3];
    const float* bias   = (const float*)d_in[4];
    const float* Wd     = (const float*)d_in[5];
    const float* bd     = (const float*)d_in[6];
    float* out = (float*)d_out;

    const size_t XP_BYTES  = (size_t)SS * BB * H3 * 2;      // 100,663,296
    const size_t WSU_BYTES = (size_t)NWG * UBYTES;          // 1,572,864
    const size_t WSW_BYTES = (size_t)32 * H3 * 8 * 2;       // 786,432
    const size_t HPUB_BYTES = 2 * (size_t)HBYTES;           // 131,072
    const size_t HLAST_BYTES = (size_t)BB * HH * 4;         // 131,072
    const size_t FLAG_BYTES = 2048;
    const size_t PART_BYTES = (size_t)393 * 64 * 2 * 4;     // 201,216

    char* ws = (char*)d_ws;
    _Float16* xp    = (_Float16*)ws;
    _Float16* wsU   = (_Float16*)(ws + XP_BYTES);
    _Float16* wsW   = (_Float16*)(ws + XP_BYTES + WSU_BYTES);
    char*     hpub  =            ws + XP_BYTES + WSU_BYTES + WSW_BYTES;
    float*    hlast = (float*)  (hpub + HPUB_BYTES);
    unsigned int* flags = (unsigned int*)(hpub + HPUB_BYTES + HLAST_BYTES);
    float* partials = (float*)(hpub + HPUB_BYTES + HLAST_BYTES + FLAG_BYTES);
    float* rowMS    = (float*)(hpub + HPUB_BYTES + HLAST_BYTES + FLAG_BYTES + PART_BYTES);

    hipFuncSetAttribute((const void*)k2_scan,
                        hipFuncAttributeMaxDynamicSharedMemorySize,
                        UBYTES + HBYTES);

    hipMemsetAsync(flags, 0, FLAG_BYTES, stream);
    hipMemsetAsync(hpub, 0, HPUB_BYTES, stream);

    kPackW<<<32 * H3 / 256, 256, 0, stream>>>(W, wsW);
    kPackU<<<NWG, 256, 0, stream>>>(U, wsU);
    k1_embed_proj<<<dim3(12, 512), 256, 0, stream>>>(tokens, emb, wsW, bias, xp);

    k2_scan<<<NWG, 128, UBYTES + HBYTES, stream>>>(xp, wsU, bias, tokens,
                                                   hpub, hlast, flags);

    k3_logits<<<393, 256, 0, stream>>>(hlast, Wd, bd, out, partials);
    k3_reduce<<<64, 64, 0, stream>>>(partials, rowMS);
    k3_softmax<<<dim3((VV + 255) / 256, BB), 256, 0, stream>>>(out, rowMS);
}

// Round 3
// 3488.836 us; speedup vs baseline: 2.1156x; 1.0419x over previous
//
#include <hip/hip_runtime.h>
#include <hip/hip_bf16.h>

#define VV 50257
#define DD 256
#define HH 512
#define BB 64
#define SS 512
#define H3 1536
#define NWG 16          // scan workgroups (1 per CU, co-resident)
#define JSL 32          // hidden units per scan WG
#define UCPAD 97        // 96 cols (3 gates x 32) + 1 pad col per k-row
#define UBYTES (64*UCPAD*16)   // 99328 B per-WG padded U slice image
#define HBYTES (BB*HH*2)       // 65536 B f16 h image, row-major [64][512]

typedef _Float16 f16x8 __attribute__((ext_vector_type(8)));
typedef _Float16 f16x4 __attribute__((ext_vector_type(4)));
typedef float f32x4 __attribute__((ext_vector_type(4)));
typedef unsigned int u32x4 __attribute__((ext_vector_type(4)));

#define AS1 __attribute__((address_space(1)))
#define AS3 __attribute__((address_space(3)))
#define GLL16(g, s) __builtin_amdgcn_global_load_lds((const AS1 char*)(g), (AS3 char*)(s), 16, 0, 0)

// ---------------------------------------------------------------------------
// Pack W (f32 [256][1536]) -> f16 k-major: elem (k,col) at [(k>>3)*1536+col]*8+(k&7)
// ---------------------------------------------------------------------------
__global__ __launch_bounds__(256) void kPackW(const float* __restrict__ W,
                                              _Float16* __restrict__ wsW) {
    int idx = blockIdx.x * 256 + threadIdx.x;     // 32 kb * 1536 col
    int kb = idx / H3, col = idx % H3;
    f16x8 v;
    #pragma unroll
    for (int e = 0; e < 8; ++e) v[e] = (_Float16)W[(size_t)(kb*8+e)*H3 + col];
    *(f16x8*)(wsW + (size_t)idx*8) = v;
}

// ---------------------------------------------------------------------------
// Pack U -> per-WG padded k-major images. WG w holds cols {g*512 + w*32 + jl}.
// Row kb (64 rows): 97 cols x 16B (col 96 = pad/dup) -> 1552 B/row.
// ---------------------------------------------------------------------------
__global__ __launch_bounds__(256) void kPackU(const float* __restrict__ U,
                                              _Float16* __restrict__ wsU) {
    int wgp = blockIdx.x;                          // 16
    for (int idx = threadIdx.x; idx < 64*UCPAD; idx += 256) {
        int kb = idx / UCPAD, c = idx % UCPAD;
        int cc = (c == 96) ? 0 : c;
        int g = cc / JSL, jl = cc % JSL;
        int gcol = g*HH + wgp*JSL + jl;
        f16x8 v;
        #pragma unroll
        for (int e = 0; e < 8; ++e) v[e] = (_Float16)U[(size_t)(kb*8+e)*H3 + gcol];
        *(f16x8*)(wsU + (size_t)wgp*(UBYTES/2) + (size_t)idx*8) = v;
    }
}

// maskbits[t] bit r = (tokens[r][t] != 0)
__global__ __launch_bounds__(256) void kMask(const int* __restrict__ tokens,
                                             unsigned long long* __restrict__ mb) {
    int t = blockIdx.x * 256 + threadIdx.x;
    if (t < SS) {
        unsigned long long m = 0ull;
        for (int r = 0; r < BB; ++r)
            m |= (unsigned long long)(tokens[r*SS + t] != 0) << r;
        mb[t] = m;
    }
}

// ---------------------------------------------------------------------------
// K1: xp[t][col][b] (f16) = (emb[tokens] @ W + b0)
// ---------------------------------------------------------------------------
__global__ __launch_bounds__(256) void k1_embed_proj(
    const int* __restrict__ tokens, const float* __restrict__ emb,
    const _Float16* __restrict__ wsW, const float* __restrict__ bias,
    _Float16* __restrict__ xp)
{
    const int s  = blockIdx.y;
    const int nt = blockIdx.x;
    const int tid = threadIdx.x;
    __shared__ _Float16 aLds[64 * 256];

    for (int c = tid; c < 64 * 32; c += 256) {
        int row = c >> 5, kc = c & 31;
        int tok = tokens[row * SS + s];
        const float* src = emb + (size_t)tok * DD + kc * 8;
        float4 f0 = *(const float4*)(src);
        float4 f1 = *(const float4*)(src + 4);
        f16x8 v;
        v[0]=(_Float16)f0.x; v[1]=(_Float16)f0.y; v[2]=(_Float16)f0.z; v[3]=(_Float16)f0.w;
        v[4]=(_Float16)f1.x; v[5]=(_Float16)f1.y; v[6]=(_Float16)f1.z; v[7]=(_Float16)f1.w;
        int byte = row * 512 + ((kc * 16) ^ ((row & 7) << 4));
        *(f16x8*)((char*)aLds + byte) = v;
    }
    __syncthreads();

    const int w = tid >> 6, l = tid & 63;
    const int l15 = l & 15, lk = l >> 4;
    const int colbase = nt * 128;
    f32x4 acc[8] = {};

    for (int ks = 0; ks < 8; ++ks) {
        int arow = 16 * w + l15;
        f16x8 aF = *(const f16x8*)((const char*)aLds + arow*512 + (((ks*32 + lk*8)*2) ^ ((arow & 7) << 4)));
        int kb = ks*4 + lk;
        #pragma unroll
        for (int ns = 0; ns < 8; ++ns) {
            int col = colbase + ns * 16 + l15;
            f16x8 bF = *(const f16x8*)(wsW + ((size_t)kb * H3 + col) * 8);
            acc[ns] = __builtin_amdgcn_mfma_f32_16x16x32_f16(aF, bF, acc[ns], 0, 0, 0);
        }
    }
    #pragma unroll
    for (int ns = 0; ns < 8; ++ns) {
        int col = colbase + ns * 16 + l15;
        float b0 = bias[col];
        f16x4 vv;
        #pragma unroll
        for (int i = 0; i < 4; ++i) vv[i] = (_Float16)(acc[ns][i] + b0);
        *(f16x4*)(xp + ((size_t)s * H3 + col) * BB + 16*w + lk*4) = vv;
    }
}

// ---------------------------------------------------------------------------
// K2: persistent GRU scan. 16 WGs x 256 thr (4 m-tile waves); U slice in LDS;
// h exchanged via double-buffered global f16 image with sc0/sc1 device-scope
// stores/loads (no threadfence, no L2 wb/inv).
// ---------------------------------------------------------------------------
__global__ __launch_bounds__(256) void k2_scan(
    const _Float16* __restrict__ xp, const _Float16* __restrict__ wsU,
    const float* __restrict__ bias, const unsigned long long* __restrict__ maskbits,
    char* __restrict__ hpub, float* __restrict__ hlast,
    unsigned int* __restrict__ flags)
{
    extern __shared__ char uLds[];
    const int wg = blockIdx.x, tid = threadIdx.x;
    const int w = tid >> 6, l = tid & 63;
    const int l15 = l & 15, lk = l >> 4;
    const int jg = wg * JSL;

    // stage resident padded U slice (linear image -> linear LDS)
    {
        const char* src = (const char*)wsU + (size_t)wg * UBYTES;
        for (int base = 0; base < UBYTES; base += 4096) {
            int off = base + tid * 16;
            if (off < UBYTES) GLL16(src + off, uLds + off);
        }
    }
    const int j0 = jg + l15, j1 = jg + 16 + l15;
    const float b1z0 = bias[H3 + j0],        b1z1 = bias[H3 + j1];
    const float b1r0 = bias[H3 + HH + j0],   b1r1 = bias[H3 + HH + j1];
    const float b1h0 = bias[H3 + 2*HH + j0], b1h1 = bias[H3 + 2*HH + j1];
    float hold[2][4] = {};
    __syncthreads();

    for (int t = 0; t < SS; ++t) {
        // issue gate-phase loads early (independent of the wait)
        const _Float16* xpt = xp + (size_t)t * H3 * BB;
        const int boff = w*16 + lk*4;
        f16x4 xz0 = *(const f16x4*)(xpt + (0*HH + j0)*BB + boff);
        f16x4 xz1 = *(const f16x4*)(xpt + (0*HH + j1)*BB + boff);
        f16x4 xr0 = *(const f16x4*)(xpt + (1*HH + j0)*BB + boff);
        f16x4 xr1 = *(const f16x4*)(xpt + (1*HH + j1)*BB + boff);
        f16x4 xh0 = *(const f16x4*)(xpt + (2*HH + j0)*BB + boff);
        f16x4 xh1 = *(const f16x4*)(xpt + (2*HH + j1)*BB + boff);
        unsigned long long mb = maskbits[t];

        // wait for h(t) from all WGs
        if (t > 0) {
            if (tid < NWG) {
                const unsigned int* fp = flags + tid * 16;
                int n = 0;
                while (__hip_atomic_load(fp, __ATOMIC_RELAXED, __HIP_MEMORY_SCOPE_AGENT) < (unsigned)t) {
                    if (++n > 3000000) break;   // safety bound
                }
            }
            __syncthreads();
        }

        // load A-fragments (16 rows x 512 k) straight to registers, L2-bypass
        const char* hsrc = hpub + (size_t)(t & 1) * HBYTES;
        unsigned long long hb = (unsigned long long)(hsrc + (w*16 + l15)*1024 + lk*16);
        u32x4 hf[16];
#define LDH(i, off) asm volatile("global_load_dwordx4 %0, %1, off offset:" off " sc0 sc1" \
                                 : "=v"(hf[i]) : "v"(hb) : "memory")
        LDH(0,"0");    LDH(1,"64");   LDH(2,"128");  LDH(3,"192");
        LDH(4,"256");  LDH(5,"320");  LDH(6,"384");  LDH(7,"448");
        LDH(8,"512");  LDH(9,"576");  LDH(10,"640"); LDH(11,"704");
        LDH(12,"768"); LDH(13,"832"); LDH(14,"896"); LDH(15,"960");
#undef LDH
        asm volatile("s_waitcnt vmcnt(0)" ::: "memory");
        __builtin_amdgcn_sched_barrier(0);

        // rec = h @ Uslice : 1 m-tile x 6 n-tiles (z0 z1 r0 r1 h0 h1) per wave
        f32x4 az0 = {}, az1 = {}, ar0 = {}, ar1 = {}, ah0 = {}, ah1 = {};
        #pragma unroll
        for (int ks = 0; ks < 16; ++ks) {
            f16x8 a = __builtin_bit_cast(f16x8, hf[ks]);
            const char* ub = uLds + (size_t)(ks*4 + lk) * (UCPAD*16) + l15*16;
            f16x8 bz0 = *(const f16x8*)(ub);
            f16x8 bz1 = *(const f16x8*)(ub + 256);
            f16x8 br0 = *(const f16x8*)(ub + 512);
            f16x8 br1 = *(const f16x8*)(ub + 768);
            f16x8 bh0 = *(const f16x8*)(ub + 1024);
            f16x8 bh1 = *(const f16x8*)(ub + 1280);
            az0 = __builtin_amdgcn_mfma_f32_16x16x32_f16(a, bz0, az0, 0, 0, 0);
            az1 = __builtin_amdgcn_mfma_f32_16x16x32_f16(a, bz1, az1, 0, 0, 0);
            ar0 = __builtin_amdgcn_mfma_f32_16x16x32_f16(a, br0, ar0, 0, 0, 0);
            ar1 = __builtin_amdgcn_mfma_f32_16x16x32_f16(a, br1, ar1, 0, 0, 0);
            ah0 = __builtin_amdgcn_mfma_f32_16x16x32_f16(a, bh0, ah0, 0, 0, 0);
            ah1 = __builtin_amdgcn_mfma_f32_16x16x32_f16(a, bh1, ah1, 0, 0, 0);
        }

        // gates
        unsigned short hv[2][4];
        #pragma unroll
        for (int nt2 = 0; nt2 < 2; ++nt2) {
            f32x4 az = nt2 ? az1 : az0;
            f32x4 ar = nt2 ? ar1 : ar0;
            f32x4 ah = nt2 ? ah1 : ah0;
            f16x4 xz = nt2 ? xz1 : xz0;
            f16x4 xr = nt2 ? xr1 : xr0;
            f16x4 xh = nt2 ? xh1 : xh0;
            float bz = nt2 ? b1z1 : b1z0;
            float br = nt2 ? b1r1 : b1r0;
            float bh = nt2 ? b1h1 : b1h0;
            #pragma unroll
            for (int i = 0; i < 4; ++i) {
                int row = w*16 + lk*4 + i;
                float z  = 1.f / (1.f + __expf(-((float)xz[i] + az[i] + bz)));
                float rg = 1.f / (1.f + __expf(-((float)xr[i] + ar[i] + br)));
                float ag = (float)xh[i] + rg * (ah[i] + bh);
                float hc = 1.f - 2.f / (__expf(2.f * ag) + 1.f);
                float hn = z * hold[nt2][i] + (1.f - z) * hc;
                if (!((mb >> row) & 1ull)) hn = hold[nt2][i];
                hold[nt2][i] = hn;
                hv[nt2][i] = __builtin_bit_cast(unsigned short, (_Float16)hn);
            }
        }

        if (t < SS - 1) {
            char* hnxt = hpub + (size_t)((t+1) & 1) * HBYTES;
            unsigned long long ha = (unsigned long long)(hnxt + (w*16 + lk*4)*1024 + (jg + l15)*2);
#define PUBH(v16, off) asm volatile("global_store_short %0, %1, off offset:" off " sc0 sc1" \
                                    :: "v"(ha), "v"((unsigned int)(v16)) : "memory")
            PUBH(hv[0][0], "0");  PUBH(hv[0][1], "1024");
            PUBH(hv[0][2], "2048"); PUBH(hv[0][3], "3072");
            PUBH(hv[1][0], "32"); PUBH(hv[1][1], "1056");
            PUBH(hv[1][2], "2080"); PUBH(hv[1][3], "3104");
#undef PUBH
            asm volatile("s_waitcnt vmcnt(0)" ::: "memory");
            __syncthreads();
            if (tid == 0)
                __hip_atomic_store(flags + wg*16, (unsigned)(t+1),
                                   __ATOMIC_RELAXED, __HIP_MEMORY_SCOPE_AGENT);
        } else {
            #pragma unroll
            for (int nt2 = 0; nt2 < 2; ++nt2)
                #pragma unroll
                for (int i = 0; i < 4; ++i) {
                    int row = w*16 + lk*4 + i;
                    hlast[row*HH + jg + nt2*16 + l15] = hold[nt2][i];
                }
        }
    }
}

// ---------------------------------------------------------------------------
// K3a: logits + per-WG softmax partials
// ---------------------------------------------------------------------------
__global__ __launch_bounds__(256) void k3_logits(
    const float* __restrict__ hin, const float* __restrict__ Wd,
    const float* __restrict__ bd, float* __restrict__ out,
    float* __restrict__ partials)
{
    const int nt = blockIdx.x;
    const int tid = threadIdx.x;
    __shared__ _Float16 hLds[64 * 512];

    for (int c = tid; c < 64 * 64; c += 256) {
        int row = c >> 6, kc = c & 63;
        const float* src = hin + row * HH + kc * 8;
        float4 f0 = *(const float4*)(src);
        float4 f1 = *(const float4*)(src + 4);
        f16x8 v;
        v[0]=(_Float16)f0.x; v[1]=(_Float16)f0.y; v[2]=(_Float16)f0.z; v[3]=(_Float16)f0.w;
        v[4]=(_Float16)f1.x; v[5]=(_Float16)f1.y; v[6]=(_Float16)f1.z; v[7]=(_Float16)f1.w;
        int byte = row * 1024 + ((kc * 16) ^ ((row & 7) << 4));
        *(f16x8*)((char*)hLds + byte) = v;
    }
    __syncthreads();

    const int w = tid >> 6, l = tid & 63;
    const int l15 = l & 15, lk = l >> 4;
    f32x4 acc[8] = {};

    for (int ks = 0; ks < 16; ++ks) {
        int arow = 16 * w + l15;
        int abyte = arow * 1024 + ((((ks * 32 + lk * 8) * 2)) ^ ((arow & 7) << 4));
        f16x8 aFrag = *(const f16x8*)((const char*)hLds + abyte);
        int krow = ks * 32 + lk * 8;
        #pragma unroll
        for (int ns = 0; ns < 8; ++ns) {
            int col = nt * 128 + ns * 16 + l15;
            f16x8 bFrag;
            if (col < VV) {
                #pragma unroll
                for (int i = 0; i < 8; ++i) bFrag[i] = (_Float16)Wd[(size_t)(krow + i) * VV + col];
            } else {
                #pragma unroll
                for (int i = 0; i < 8; ++i) bFrag[i] = (_Float16)0.f;
            }
            acc[ns] = __builtin_amdgcn_mfma_f32_16x16x32_f16(aFrag, bFrag, acc[ns], 0, 0, 0);
        }
    }

    float lg[8][4];
    float m[4] = {-3.4e38f, -3.4e38f, -3.4e38f, -3.4e38f};
    float ss[4] = {0.f, 0.f, 0.f, 0.f};
    #pragma unroll
    for (int ns = 0; ns < 8; ++ns) {
        int col = nt * 128 + ns * 16 + l15;
        bool ok = col < VV;
        float bv = ok ? bd[col] : 0.f;
        #pragma unroll
        for (int i = 0; i < 4; ++i) {
            int row = 16 * w + lk * 4 + i;
            float v = acc[ns][i] + bv;
            lg[ns][i] = ok ? v : -3.4e38f;
            if (ok) {
                out[(size_t)row * VV + col] = v;
                m[i] = fmaxf(m[i], v);
            }
        }
    }
    #pragma unroll
    for (int i = 0; i < 4; ++i) {
        #pragma unroll
        for (int ns = 0; ns < 8; ++ns)
            if (lg[ns][i] > -3.3e38f) ss[i] += __expf(lg[ns][i] - m[i]);
        for (int d = 1; d < 16; d <<= 1) {
            float m2 = __shfl_xor(m[i], d);
            float s2 = __shfl_xor(ss[i], d);
            float nM = fmaxf(m[i], m2);
            ss[i] = ss[i] * __expf(m[i] - nM) + s2 * __expf(m2 - nM);
            m[i] = nM;
        }
        if (l15 == 0) {
            int row = 16 * w + lk * 4 + i;
            partials[((size_t)nt * 64 + row) * 2 + 0] = m[i];
            partials[((size_t)nt * 64 + row) * 2 + 1] = ss[i];
        }
    }
}

__global__ __launch_bounds__(64) void k3_reduce(
    const float* __restrict__ partials, float* __restrict__ rowMS)
{
    int row = blockIdx.x, l = threadIdx.x;
    float M = -3.4e38f, Ssum = 0.f;
    for (int p = l; p < 393; p += 64) {
        float mp = partials[((size_t)p * 64 + row) * 2 + 0];
        float sp = partials[((size_t)p * 64 + row) * 2 + 1];
        float nM = fmaxf(M, mp);
        Ssum = Ssum * __expf(M - nM) + sp * __expf(mp - nM);
        M = nM;
    }
    for (int d = 1; d < 64; d <<= 1) {
        float m2 = __shfl_xor(M, d), s2 = __shfl_xor(Ssum, d);
        float nM = fmaxf(M, m2);
        Ssum = Ssum * __expf(M - nM) + s2 * __expf(m2 - nM);
        M = nM;
    }
    if (l == 0) { rowMS[row * 2] = M; rowMS[row * 2 + 1] = Ssum; }
}

__global__ __launch_bounds__(256) void k3_softmax(
    float* __restrict__ out, const float* __restrict__ rowMS)
{
    int col = blockIdx.x * 256 + threadIdx.x;
    int row = blockIdx.y;
    if (col < VV) {
        float M = rowMS[row * 2], Sv = rowMS[row * 2 + 1];
        size_t idx = (size_t)row * VV + col;
        out[idx] = __expf(out[idx] - M) / Sv;
    }
}

// ---------------------------------------------------------------------------
extern "C" void kernel_launch(void* const* d_in, const int* in_sizes, int n_in,
                              void* d_out, int out_size, void* d_ws, size_t ws_size,
                              hipStream_t stream) {
    const int*   tokens = (const int*)  d_in[0];
    const float* emb    = (const float*)d_in[1];
    const float* W      = (const float*)d_in[2];
    const float* U      = (const float*)d_in[3];
    const float* bias   = (const float*)d_in[4];
    const float* Wd     = (const float*)d_in[5];
    const float* bd     = (const float*)d_in[6];
    float* out = (float*)d_out;

    const size_t XP_BYTES   = (size_t)SS * BB * H3 * 2;     // 100,663,296
    const size_t WSU_BYTES  = (size_t)NWG * UBYTES;         // 1,589,248
    const size_t WSW_BYTES  = (size_t)32 * H3 * 8 * 2;      // 786,432
    const size_t HPUB_BYTES = 2 * (size_t)HBYTES;           // 131,072
    const size_t HLAST_BYTES= (size_t)BB * HH * 4;          // 131,072
    const size_t FLAG_BYTES = 2048;
    const size_t MASK_BYTES = (size_t)SS * 8;               // 4,096
    const size_t PART_BYTES = (size_t)393 * 64 * 2 * 4;     // 201,216

    char* ws = (char*)d_ws;
    _Float16* xp    = (_Float16*)ws;
    _Float16* wsU   = (_Float16*)(ws + XP_BYTES);
    _Float16* wsW   = (_Float16*)(ws + XP_BYTES + WSU_BYTES);
    char*     hpub  =            ws + XP_BYTES + WSU_BYTES + WSW_BYTES;
    float*    hlast = (float*)  (hpub + HPUB_BYTES);
    unsigned int* flags = (unsigned int*)(hpub + HPUB_BYTES + HLAST_BYTES);
    unsigned long long* maskb = (unsigned long long*)(hpub + HPUB_BYTES + HLAST_BYTES + FLAG_BYTES);
    float* partials = (float*)(hpub + HPUB_BYTES + HLAST_BYTES + FLAG_BYTES + MASK_BYTES);
    float* rowMS    = (float*)(hpub + HPUB_BYTES + HLAST_BYTES + FLAG_BYTES + MASK_BYTES + PART_BYTES);

    hipFuncSetAttribute((const void*)k2_scan,
                        hipFuncAttributeMaxDynamicSharedMemorySize, UBYTES);

    hipMemsetAsync(flags, 0, FLAG_BYTES, stream);
    hipMemsetAsync(hpub, 0, HPUB_BYTES, stream);

    kPackW<<<32 * H3 / 256, 256, 0, stream>>>(W, wsW);
    kPackU<<<NWG, 256, 0, stream>>>(U, wsU);
    kMask<<<2, 256, 0, stream>>>(tokens, maskb);
    k1_embed_proj<<<dim3(12, 512), 256, 0, stream>>>(tokens, emb, wsW, bias, xp);

    k2_scan<<<NWG, 256, UBYTES, stream>>>(xp, wsU, bias, maskb, hpub, hlast, flags);

    k3_logits<<<393, 256, 0, stream>>>(hlast, Wd, bd, out, partials);
    k3_reduce<<<64, 64, 0, stream>>>(partials, rowMS);
    k3_softmax<<<dim3((VV + 255) / 256, BB), 256, 0, stream>>>(out, rowMS);
}